// Round 14
// baseline (19.399 us; speedup 1.0000x reference)
//
#include <hip/hip_runtime.h>

#define B_ 4
#define J_ 8160               // 68*120 cells per batch
#define HF 544
#define WF 960
#define TS 32
#define TYN 17
#define NTX 10                // tile-TRIPLES per row (96px wide each)
#define NTPB (NTX*TYN)        // 170 triples per batch; grid = 680 blocks
#define R2COEF 23.0259f       // 2*ln(1e5): exact per-cell cut (d^2 <= R2COEF*var)

typedef _Float16 half8 __attribute__((ext_vector_type(8)));
typedef float floatx16 __attribute__((ext_vector_type(16)));

// SINGLE plain dispatch. R13 confirmed: kernel time ~ blocks x per-block scan;
// widen the block to amortize the scan further. One block per 96x32 tile-
// TRIPLE (680 blocks): scan 133->88 MB L2, 8.3M->5.5M position tests, while
// keeping R10/R13's independent-load scan structure exactly (R11 lesson).
// Wave w scans cells [w*2048,(w+1)*2048), 2 cells/lane/iter, clamped-box test
// vs the 96x32 union, ballot-compacts records (mx,my,1/(2v),cf) into a
// per-wave LDS queue. Drain: 8 ey (shared) + 8 exL/exM/exR exps, THREE
// v_mfma_f32_32x32x16_f16 into per-tile accumulators (layout validated
// R3-R13: cell -> same k-slot (half,i) in A and B; C/D
// row=(r&3)+8*(r>>2)+4*half). Epilogue reduces/writes the three tiles
// sequentially from the same 16KB LDS arena. (256,4): 128-VGPR budget covers
// 48 acc regs + ~55 scan/drain temps (est ~105, no spill).
__global__ __launch_bounds__(256, 4) void pif_tri(const float2* __restrict__ mean,
                                                  const float*  __restrict__ var,
                                                  const float*  __restrict__ conf,
                                                  float* __restrict__ out) {
    __shared__ float4 qbuf[4][256];    // per-wave queues; re-used as red[] later
    int wid  = threadIdx.x >> 6;
    int lane = threadIdx.x & 63;
    int tri  = blockIdx.x;             // 0..169
    int b    = blockIdx.y;

    int pty = tri / NTX;
    int ptx = tri - pty * NTX;

    const float4* mb4 = (const float4*)(mean + (size_t)b * J_);  // 2 cells/elt
    const float2* vb2 = (const float2*)(var  + (size_t)b * J_);
    const float2* cb2 = (const float2*)(conf + (size_t)b * J_);

    float4* q = qbuf[wid];
    int qn = 0;

    float x0 = (float)(ptx * 96), y0 = (float)(pty * TS);
    float x1 = x0 + 95.f,         y1 = y0 + 31.f;   // union box of the 3 tiles
    int   lx = lane & 31, half = lane >> 5;
    float xfL = x0 + (float)lx;
    float xfM = x0 + 32.f + (float)lx;
    float xfR = x0 + 64.f + (float)lx;
    float yf  = y0 + (float)lx;
    const unsigned long long below = (1ull << lane) - 1ull;

    floatx16 accL = {}, accM = {}, accR = {};

    auto drain16 = [&](int base) {     // consumes q[base..base+15], LDS-only
        half8 af, bfl, bfm, bfr;
        #pragma unroll
        for (int i = 0; i < 8; ++i) {
            float4 e = q[base + 8 * half + i];   // uniform per half-wave: broadcast
            float dy  = yf  - e.y;
            float dxl = xfL - e.x;
            float dxm = xfM - e.x;
            float dxr = xfR - e.x;
            af[i]  = (_Float16)__expf(-dy * dy * e.z);
            float c = e.w;
            bfl[i] = (_Float16)(c * __expf(-dxl * dxl * e.z));  // w=0 -> inert
            bfm[i] = (_Float16)(c * __expf(-dxm * dxm * e.z));
            bfr[i] = (_Float16)(c * __expf(-dxr * dxr * e.z));
        }
        accL = __builtin_amdgcn_mfma_f32_32x32x16_f16(af, bfl, accL, 0, 0, 0);
        accM = __builtin_amdgcn_mfma_f32_32x32x16_f16(af, bfm, accM, 0, 0, 0);
        accR = __builtin_amdgcn_mfma_f32_32x32x16_f16(af, bfr, accR, 0, 0, 0);
    };

    int jbase = wid * 2048;                    // this wave's padded slice
    for (int s = 0; s < 16; ++s) {
        int j0 = jbase + s * 128 + 2 * lane;   // even
        bool valid = j0 < J_;                  // j0 even: valid => j0+1 valid too
        int  jh = (valid ? j0 : 0) >> 1;       // safe aligned load index

        float4 mm = mb4[jh];                   // means of the 2 cells
        float2 vv = vb2[jh];                   // their variances
        float2 cc = cb2[jh];                   // their confidences

        float cx0 = fminf(fmaxf(mm.x, x0), x1);
        float cy0 = fminf(fmaxf(mm.y, y0), y1);
        float cx1 = fminf(fmaxf(mm.z, x0), x1);
        float cy1 = fminf(fmaxf(mm.w, y0), y1);
        float dx0 = mm.x - cx0, dy0 = mm.y - cy0;
        float dx1 = mm.z - cx1, dy1 = mm.w - cy1;
        bool p0 = valid & (cc.x > 0.1f) & (dx0 * dx0 + dy0 * dy0 <= R2COEF * vv.x);
        bool p1 = valid & (cc.y > 0.1f) & (dx1 * dx1 + dy1 * dy1 <= R2COEF * vv.y);

        // compact cell 0 records (cap 256; guard keeps write index <= 206)
        unsigned long long m0 = __ballot(p0);
        if (p0) q[qn + __popcll(m0 & below)] =
            make_float4(mm.x, mm.y, __builtin_amdgcn_rcpf(2.0f * vv.x), cc.x);
        qn += __popcll(m0);
        if (__builtin_expect(qn >= 144, 0)) {
            while (qn >= 16) { qn -= 16; drain16(qn); }
        }
        // compact cell 1 records
        unsigned long long m1 = __ballot(p1);
        if (p1) q[qn + __popcll(m1 & below)] =
            make_float4(mm.z, mm.w, __builtin_amdgcn_rcpf(2.0f * vv.y), cc.y);
        qn += __popcll(m1);
        if (__builtin_expect(qn >= 144, 0)) {
            while (qn >= 16) { qn -= 16; drain16(qn); }
        }
    }

    while (qn >= 16) { qn -= 16; drain16(qn); }
    if (qn > 0) {                              // pad tail to a full chunk
        if (lane >= qn && lane < 16)
            q[lane] = make_float4(0.f, 0.f, 0.f, 0.f);   // cf=0: inert
        drain16(0);                            // wave-local LDS: no barrier needed
    }

    // ---- Epilogue: queues dead; alias qbuf as red[4][32][32], three passes
    float (*red)[32][32] = (float (*)[32][32])qbuf;      // 16 KB alias
    int th = threadIdx.x;

    #pragma unroll
    for (int pass = 0; pass < 3; ++pass) {
        const floatx16& a = (pass == 0) ? accL : (pass == 1) ? accM : accR;
        __syncthreads();
        #pragma unroll
        for (int r = 0; r < 16; ++r) {
            int row = (r & 3) + 8 * (r >> 2) + 4 * half;
            red[wid][row][lx] = a[r];          // 2-way bank alias: free
        }
        __syncthreads();
        #pragma unroll
        for (int k = 0; k < 4; ++k) {
            int p   = th + 256 * k;
            int row = p >> 5, col = p & 31;
            float s = red[0][row][col] + red[1][row][col]
                    + red[2][row][col] + red[3][row][col];
            out[((size_t)(b * HF + pty * TS + row)) * WF
                + (ptx * 96 + pass * 32 + col)] = s;
        }
    }
}

extern "C" void kernel_launch(void* const* d_in, const int* in_sizes, int n_in,
                              void* d_out, int out_size, void* d_ws, size_t ws_size,
                              hipStream_t stream) {
    const float2* mean = (const float2*)d_in[0];
    const float*  var  = (const float*)d_in[1];
    const float*  conf = (const float*)d_in[2];
    float* out = (float*)d_out;
    (void)d_ws; (void)ws_size;

    pif_tri<<<dim3(NTPB, B_), 256, 0, stream>>>(mean, var, conf, out);
}

// Round 15
// 18.423 us; speedup vs baseline: 1.0530x; 1.0530x over previous
//
#include <hip/hip_runtime.h>

#define B_ 4
#define J_ 8160               // 68*120 cells per batch
#define NQ_ 2040              // quads per batch
#define HF 544
#define WF 960
#define TS 32
#define TYN 17
#define NPX 15                // tile-PAIRS per row (64px wide)
#define NPPB (NPX*TYN)        // 255 pairs/batch; grid = 1020 blocks = 3.98/CU
#define R2COEF 23.0259f       // 2*ln(1e5): exact per-cell cut (d^2 <= R2COEF*var)

typedef _Float16 half8 __attribute__((ext_vector_type(8)));
typedef float floatx16 __attribute__((ext_vector_type(16)));

// SINGLE plain dispatch; R13 pair structure (the granularity optimum: 1020
// blocks = balanced 4/CU) with the scan rebuilt as quad-per-lane:
//   - 4 cells/lane/iter, 8 iters; ALL loads unconditional & independent
//     (2x mean float4 + var float4 + conf float4 in flight together) --
//     R11's quad regressed from predicated dependent loads + 64-VGPR spill;
//     here loads are independent and (256,4) gives 128 VGPR.
//   - single-segment compaction: 4 ballots -> all write positions derived
//     from masks, ONE qn update + ONE drain guard per iter (serialized
//     chain segments 32 -> 8 per wave).
// Queue cap 512 (32KB LDS, 4 blocks/CU retained; worst-case write index
// qn(<=255) + 255 = 510 < 512 even if every lane passes all 4 cells).
// Drain: 8 ey (shared) + 8 exL + 8 exR, TWO v_mfma_f32_32x32x16_f16
// (layout validated R3-R14). Epilogue: LDS-reduce, write both tiles.
__global__ __launch_bounds__(256, 4) void pif_pair(const float2* __restrict__ mean,
                                                   const float*  __restrict__ var,
                                                   const float*  __restrict__ conf,
                                                   float* __restrict__ out) {
    __shared__ float4 qbuf[4][512];    // per-wave queues (32KB); red[] alias later
    int wid  = threadIdx.x >> 6;
    int lane = threadIdx.x & 63;
    int pair = blockIdx.x;             // 0..254
    int b    = blockIdx.y;

    int pty = pair / NPX;
    int ptx = pair - pty * NPX;

    const float4* mb4 = (const float4*)(mean + (size_t)b * J_);  // [2k],[2k+1]
    const float4* vb4 = (const float4*)(var  + (size_t)b * J_);  // [k]: 4 vars
    const float4* cb4 = (const float4*)(conf + (size_t)b * J_);  // [k]: 4 confs

    float4* q = qbuf[wid];
    int qn = 0;

    float x0 = (float)(ptx * 64), y0 = (float)(pty * TS);
    float x1 = x0 + 63.f,         y1 = y0 + 31.f;   // union box of the 2 tiles
    int   lx = lane & 31, half = lane >> 5;
    float xfL = x0 + (float)lx;
    float xfR = x0 + 32.f + (float)lx;
    float yf  = y0 + (float)lx;
    const unsigned long long below = (1ull << lane) - 1ull;

    floatx16 accL = {}, accR = {};

    auto drain16 = [&](int base) {     // consumes q[base..base+15], LDS-only
        half8 af, bfl, bfr;
        #pragma unroll
        for (int i = 0; i < 8; ++i) {
            float4 e = q[base + 8 * half + i];   // uniform per half-wave: broadcast
            float dy  = yf  - e.y;
            float dxl = xfL - e.x;
            float dxr = xfR - e.x;
            af[i]  = (_Float16)__expf(-dy * dy * e.z);
            float c = e.w;
            bfl[i] = (_Float16)(c * __expf(-dxl * dxl * e.z));  // w=0 -> inert
            bfr[i] = (_Float16)(c * __expf(-dxr * dxr * e.z));
        }
        accL = __builtin_amdgcn_mfma_f32_32x32x16_f16(af, bfl, accL, 0, 0, 0);
        accR = __builtin_amdgcn_mfma_f32_32x32x16_f16(af, bfr, accR, 0, 0, 0);
    };

    // clamped-point squared distance to the union box
    auto pdist2 = [&](float mx, float my) {
        float ddx = mx - fminf(fmaxf(mx, x0), x1);
        float ddy = my - fminf(fmaxf(my, y0), y1);
        return ddx * ddx + ddy * ddy;
    };

    const int kbase = wid * 512;               // this wave's 512 quads
    for (int s = 0; s < 8; ++s) {
        int  k     = kbase + s * 64 + lane;    // quad = cells 4k..4k+3
        bool valid = k < NQ_;
        int  kc    = valid ? k : 0;

        float4 m01 = mb4[2 * kc];              // all 4 loads independent,
        float4 m23 = mb4[2 * kc + 1];          // issued back-to-back
        float4 vv  = vb4[kc];
        float4 cc  = cb4[kc];

        float dd0 = pdist2(m01.x, m01.y);
        float dd1 = pdist2(m01.z, m01.w);
        float dd2 = pdist2(m23.x, m23.y);
        float dd3 = pdist2(m23.z, m23.w);
        bool p0 = valid & (cc.x > 0.1f) & (dd0 <= R2COEF * vv.x);
        bool p1 = valid & (cc.y > 0.1f) & (dd1 <= R2COEF * vv.y);
        bool p2 = valid & (cc.z > 0.1f) & (dd2 <= R2COEF * vv.z);
        bool p3 = valid & (cc.w > 0.1f) & (dd3 <= R2COEF * vv.w);

        // 4 ballots, positions derived from masks; ONE qn update per iter
        unsigned long long m0 = __ballot(p0);
        unsigned long long m1 = __ballot(p1);
        unsigned long long m2 = __ballot(p2);
        unsigned long long m3 = __ballot(p3);
        int c0 = __popcll(m0), c1 = __popcll(m1), c2 = __popcll(m2);
        if (p0) q[qn + __popcll(m0 & below)] =
            make_float4(m01.x, m01.y, __builtin_amdgcn_rcpf(2.0f * vv.x), cc.x);
        if (p1) q[qn + c0 + __popcll(m1 & below)] =
            make_float4(m01.z, m01.w, __builtin_amdgcn_rcpf(2.0f * vv.y), cc.y);
        if (p2) q[qn + c0 + c1 + __popcll(m2 & below)] =
            make_float4(m23.x, m23.y, __builtin_amdgcn_rcpf(2.0f * vv.z), cc.z);
        if (p3) q[qn + c0 + c1 + c2 + __popcll(m3 & below)] =
            make_float4(m23.z, m23.w, __builtin_amdgcn_rcpf(2.0f * vv.w), cc.w);
        qn += c0 + c1 + c2 + __popcll(m3);

        if (__builtin_expect(qn >= 256, 0)) {  // cold: keeps qn <= 255 post-iter
            while (qn >= 16) { qn -= 16; drain16(qn); }
        }
    }

    while (qn >= 16) { qn -= 16; drain16(qn); }
    if (qn > 0) {                              // pad tail to a full chunk
        if (lane >= qn && lane < 16)
            q[lane] = make_float4(0.f, 0.f, 0.f, 0.f);   // cf=0: inert
        drain16(0);                            // wave-local LDS: no barrier needed
    }

    // ---- Epilogue: queues dead; alias qbuf as red[4][32][32], two passes
    float (*red)[32][32] = (float (*)[32][32])qbuf;      // first 16 KB
    int th = threadIdx.x;

    __syncthreads();
    #pragma unroll
    for (int r = 0; r < 16; ++r) {
        int row = (r & 3) + 8 * (r >> 2) + 4 * half;
        red[wid][row][lx] = accL[r];           // 2-way bank alias: free
    }
    __syncthreads();
    #pragma unroll
    for (int kk = 0; kk < 4; ++kk) {
        int p   = th + 256 * kk;
        int row = p >> 5, col = p & 31;
        float s = red[0][row][col] + red[1][row][col]
                + red[2][row][col] + red[3][row][col];
        out[((size_t)(b * HF + pty * TS + row)) * WF + (ptx * 64 + col)] = s;
    }

    __syncthreads();
    #pragma unroll
    for (int r = 0; r < 16; ++r) {
        int row = (r & 3) + 8 * (r >> 2) + 4 * half;
        red[wid][row][lx] = accR[r];
    }
    __syncthreads();
    #pragma unroll
    for (int kk = 0; kk < 4; ++kk) {
        int p   = th + 256 * kk;
        int row = p >> 5, col = p & 31;
        float s = red[0][row][col] + red[1][row][col]
                + red[2][row][col] + red[3][row][col];
        out[((size_t)(b * HF + pty * TS + row)) * WF + (ptx * 64 + 32 + col)] = s;
    }
}

extern "C" void kernel_launch(void* const* d_in, const int* in_sizes, int n_in,
                              void* d_out, int out_size, void* d_ws, size_t ws_size,
                              hipStream_t stream) {
    const float2* mean = (const float2*)d_in[0];
    const float*  var  = (const float*)d_in[1];
    const float*  conf = (const float*)d_in[2];
    float* out = (float*)d_out;
    (void)d_ws; (void)ws_size;

    pif_pair<<<dim3(NPPB, B_), 256, 0, stream>>>(mean, var, conf, out);
}